// Round 7
// baseline (615.917 us; speedup 1.0000x reference)
//
#include <hip/hip_runtime.h>
#include <cstdint>
#include <cstddef>

#define M_DIM 8192
#define N_DIM 4096
#define K_DIM 4096

typedef __attribute__((ext_vector_type(8))) short bf16x8;
typedef __attribute__((ext_vector_type(4))) float floatx4;

__device__ __forceinline__ ushort f2bf_rne(float f) {
    union { float f; uint32_t u; } a;
    a.f = f;
    uint32_t u = a.u;
    uint32_t r = (u + 0x7fffu + ((u >> 16) & 1u)) >> 16;
    return (ushort)r;
}

// packed RNE f32x2 -> bf16x2 (single HW instr; RNE matches f2bf_rne for
// normal floats). No builtin on gfx950 (m240) -> inline asm.
__device__ __forceinline__ uint32_t cvtpk_bf16(float lo, float hi) {
    uint32_t r;
    asm("v_cvt_pk_bf16_f32 %0, %1, %2" : "=v"(r) : "v"(lo), "v"(hi));
    return r;
}

// ---------------------------------------------------------------------------
// Kernel 1: packed int4 (one signed byte per int32) -> dequant -> bf16 (RNE)
// ---------------------------------------------------------------------------
__global__ void dequant_w_kernel(const int4* __restrict__ pw,
                                 const float* __restrict__ scales,
                                 const float* __restrict__ zps,
                                 uint4* __restrict__ wb, int np4) {
    int p4 = blockIdx.x * blockDim.x + threadIdx.x;
    if (p4 >= np4) return;
    int p = p4 * 4;
    int g = p >> 18;
    float s = scales[g];
    float b = -zps[g] * s;
    int4 v = pw[p4];
    int vv[4] = { v.x, v.y, v.z, v.w };
    ushort o[8];
#pragma unroll
    for (int j = 0; j < 4; ++j) {
        int lo = ((int)((uint32_t)vv[j] << 28)) >> 28;
        int hi = ((int)((uint32_t)vv[j] << 24)) >> 28;
        o[2 * j]     = f2bf_rne(fmaf((float)lo, s, b));
        o[2 * j + 1] = f2bf_rne(fmaf((float)hi, s, b));
    }
    uint4 st;
    st.x = (uint32_t)o[0] | ((uint32_t)o[1] << 16);
    st.y = (uint32_t)o[2] | ((uint32_t)o[3] << 16);
    st.z = (uint32_t)o[4] | ((uint32_t)o[5] << 16);
    st.w = (uint32_t)o[6] | ((uint32_t)o[7] << 16);
    wb[p4] = st;
}

// ---------------------------------------------------------------------------
// Kernel 2: 256x256 pipelined GEMM with FUSED x fp32->bf16 A-staging.
// X [M][K] fp32 row-major, B [N][K] bf16 row-major. C = X*B^T + bias.
// R5's proven flat schedule (best: 230us, 57.4% MfmaUtil) + T14 reg-staged A:
//   per step t (tile t computed from ring slot t&3):
//     vmcnt(2)  -> rA (A fp32 of tile t+2, loaded at t-1) ready AND
//                  B(t+1) gload_lds landed  [one in-order counted wait:
//                  per-step vmem issue order is A4 then B2, so completing
//                  down to 2 drains ...,B2(t+1),A4(t+2), leaves B2(t+2)]
//     cvt_pk x8 -> 2x swizzled ds_write_b128 into slot (t+2)&3
//     issue A4(t+3) fp32 loads -> rA     [sched_barrier pins A before B]
//     G1: 4 ds_read afb (A rows4-7 of t) + STAGE_B(t+3) | 8 MFMA (A,i=0,1)
//     G2: 4 ds_read bfn (B of t+1)                      | 8 MFMA (A,i=2,3)
//     G3: 4 ds_read afn (A rows0-3 of t+1)
//     lgkmcnt(8) -> writes + afb done (writes are oldest; 8 = bfn+afn fly)
//                                                        | 16 MFMA (B)
//     s_barrier  [no vmcnt here: all certs at step top]
// Ring-of-4 hazards unchanged from R5 (slot t+2 = slot of t-2, freed at
// beta(t-2); A(t+1) written at t-1, published by lgkmcnt(8)+barrier).
//
// T2 swizzle: slot' = slot ^ ((row>>1)&3).
//   B: inverse-swizzled global source (gload_lds dest linear).
//   A: swizzle applied directly on ds_write address (we control it now);
//      verified conflict-free: each 8-lane write group covers all 32 banks
//      exactly once. A global reads are linear fp32 rows.
//   Frag reads: fcol = ((lane>>4) ^ ((frow>>1)&3))*8 (per-lane constant).
// ---------------------------------------------------------------------------
#define TBM 256
#define TBN 256
#define TBK 32
#define NT  (K_DIM / TBK)        // 128 K-steps
#define A_E 8192                 // A region elements per slot (256*32)
#define SLOT_E 16384             // slot elements (A 16KB + B 16KB)

__global__ __launch_bounds__(512, 2)
void gemm_fused_256(const float* __restrict__ X,
                    const ushort* __restrict__ B,
                    const float* __restrict__ bias,
                    float* __restrict__ C) {
    __shared__ ushort lds[4 * SLOT_E];   // 128 KiB

    const int tid  = threadIdx.x;
    const int lane = tid & 63;
    const int wave = tid >> 6;
    const int wm   = wave >> 2;          // 0..1
    const int wn   = wave & 3;           // 0..3

    // T1: XCD-chunked bijective swizzle (nwg = 512, % 8 == 0)
    const int nwg = gridDim.x;
    const int cpx = nwg >> 3;
    const int bid = blockIdx.x;
    const int swz = (bid & 7) * cpx + (bid >> 3);
    const int bn  = swz & (N_DIM / TBN - 1);
    const int bm  = swz / (N_DIM / TBN);

    const ushort* Bb = B + (size_t)(bn * TBN) * K_DIM;

    // B staging (gload_lds, inverse-swizzled source) — unchanged from R5
    const int srow = tid >> 2;
    const int scolB = (((tid & 3) ^ ((tid >> 3) & 3)) * 8);
    const ushort* gB0 = Bb + (size_t)srow * K_DIM + scolB;
    const ushort* gB1 = gB0 + (size_t)128 * K_DIM;
    const int wdst = wave * 512;

    // A staging (fused cvt + swizzled ds_write): thread covers row tid>>1,
    // k-half (tid&1)*16 -> 16 fp32 -> 8 u32 bf16 -> 2x b128 at slots
    // s1=(2h)^q, s2=s1^1 where q=(row>>1)&3.
    const int wrow = tid >> 1;
    const int wh   = tid & 1;
    const int wq   = (wrow >> 1) & 3;
    const int we1  = wrow * TBK + (((2 * wh) ^ wq) * 8);  // element offset
    const int we2  = we1 ^ 8;
    const float* gX = X + (size_t)(bm * TBM + wrow) * K_DIM + wh * 16;

    // MFMA fragment addressing (T2-swizzled, per-lane constant)
    const int frow = lane & 15;
    const int fcol = (((lane >> 4) ^ ((frow >> 1) & 3)) * 8);
    const int aoff = (wm * 128 + frow) * TBK + fcol;
    const int boff = A_E + (wn * 64 + frow) * TBK + fcol;

    floatx4 acc[8][4] = {};
    float4 rA0, rA1, rA2, rA3;

#define LOAD_A(tt)                                                            \
    {                                                                          \
        const int k0n = ((tt) & (NT - 1)) * TBK;                               \
        rA0 = *(const float4*)(gX + k0n);                                      \
        rA1 = *(const float4*)(gX + k0n + 4);                                  \
        rA2 = *(const float4*)(gX + k0n + 8);                                  \
        rA3 = *(const float4*)(gX + k0n + 12);                                 \
    }
#define WRITE_A(tt)                                                           \
    {                                                                          \
        ushort* wp = (ushort*)lds + ((tt) & 3) * SLOT_E;                       \
        uint4 v1, v2;                                                          \
        v1.x = cvtpk_bf16(rA0.x, rA0.y); v1.y = cvtpk_bf16(rA0.z, rA0.w);      \
        v1.z = cvtpk_bf16(rA1.x, rA1.y); v1.w = cvtpk_bf16(rA1.z, rA1.w);      \
        v2.x = cvtpk_bf16(rA2.x, rA2.y); v2.y = cvtpk_bf16(rA2.z, rA2.w);      \
        v2.z = cvtpk_bf16(rA3.x, rA3.y); v2.w = cvtpk_bf16(rA3.z, rA3.w);      \
        *(uint4*)(wp + we1) = v1;                                              \
        *(uint4*)(wp + we2) = v2;                                              \
    }
#define STAGE_B(tt)                                                           \
    {                                                                          \
        const int k0s = ((tt) & (NT - 1)) * TBK;                               \
        ushort* d = (ushort*)lds + ((tt) & 3) * SLOT_E + A_E + wdst;           \
        __builtin_amdgcn_global_load_lds(                                      \
            (const __attribute__((address_space(1))) void*)(gB0 + k0s),        \
            (__attribute__((address_space(3))) void*)d, 16, 0, 0);             \
        __builtin_amdgcn_global_load_lds(                                      \
            (const __attribute__((address_space(1))) void*)(gB1 + k0s),        \
            (__attribute__((address_space(3))) void*)(d + 4096), 16, 0, 0);    \
    }

#define BODY(T, afc, bfc, afn, bfn)                                           \
    {                                                                          \
        /* top: certify rA(t+2) + B(t+1); write A(t+2); issue A(t+3) */        \
        asm volatile("s_waitcnt vmcnt(2)" ::: "memory");                       \
        __builtin_amdgcn_sched_barrier(0);                                     \
        WRITE_A((T) + 2)                                                       \
        LOAD_A((T) + 3)                                                        \
        __builtin_amdgcn_sched_barrier(0);                                     \
        const ushort* bcur = lds + ((T) & 3) * SLOT_E;                         \
        const ushort* bnxt = lds + (((T) + 1) & 3) * SLOT_E;                   \
        bf16x8 afb[4];                                                         \
        /* G1: afb reads + B stage */                                          \
        _Pragma("unroll")                                                      \
        for (int i = 0; i < 4; ++i)                                            \
            afb[i] = *(const bf16x8*)(bcur + aoff + (4 + i) * 512);            \
        STAGE_B((T) + 3)                                                       \
        __builtin_amdgcn_sched_barrier(0);                                     \
        __builtin_amdgcn_s_setprio(1);                                         \
        _Pragma("unroll")                                                      \
        for (int i = 0; i < 2; ++i)                                            \
            _Pragma("unroll")                                                  \
            for (int j = 0; j < 4; ++j)                                        \
                acc[i][j] = __builtin_amdgcn_mfma_f32_16x16x32_bf16(           \
                    afc[i], bfc[j], acc[i][j], 0, 0, 0);                       \
        __builtin_amdgcn_s_setprio(0);                                         \
        __builtin_amdgcn_sched_barrier(0);                                     \
        /* G2: bfn reads */                                                    \
        _Pragma("unroll")                                                      \
        for (int j = 0; j < 4; ++j)                                            \
            bfn[j] = *(const bf16x8*)(bnxt + boff + j * 512);                  \
        __builtin_amdgcn_sched_barrier(0);                                     \
        __builtin_amdgcn_s_setprio(1);                                         \
        _Pragma("unroll")                                                      \
        for (int i = 2; i < 4; ++i)                                            \
            _Pragma("unroll")                                                  \
            for (int j = 0; j < 4; ++j)                                        \
                acc[i][j] = __builtin_amdgcn_mfma_f32_16x16x32_bf16(           \
                    afc[i], bfc[j], acc[i][j], 0, 0, 0);                       \
        __builtin_amdgcn_s_setprio(0);                                         \
        __builtin_amdgcn_sched_barrier(0);                                     \
        /* G3: afn reads */                                                    \
        _Pragma("unroll")                                                      \
        for (int i = 0; i < 4; ++i)                                            \
            afn[i] = *(const bf16x8*)(bnxt + aoff + i * 512);                  \
        __builtin_amdgcn_sched_barrier(0);                                     \
        /* lgkm queue: [w1,w2, afb x4, bfn x4, afn x4] = 14; <=8 left means  */\
        /* writes + afb complete (bfn/afn stay outstanding across barrier)  */ \
        asm volatile("s_waitcnt lgkmcnt(8)" ::: "memory");                     \
        __builtin_amdgcn_sched_barrier(0);                                     \
        __builtin_amdgcn_s_setprio(1);                                         \
        _Pragma("unroll")                                                      \
        for (int i = 0; i < 2; ++i)                                            \
            _Pragma("unroll")                                                  \
            for (int j = 0; j < 4; ++j)                                        \
                acc[4 + i][j] = __builtin_amdgcn_mfma_f32_16x16x32_bf16(       \
                    afb[i], bfc[j], acc[4 + i][j], 0, 0, 0);                   \
        __builtin_amdgcn_s_setprio(0);                                         \
        __builtin_amdgcn_sched_barrier(0);                                     \
        __builtin_amdgcn_s_setprio(1);                                         \
        _Pragma("unroll")                                                      \
        for (int i = 2; i < 4; ++i)                                            \
            _Pragma("unroll")                                                  \
            for (int j = 0; j < 4; ++j)                                        \
                acc[4 + i][j] = __builtin_amdgcn_mfma_f32_16x16x32_bf16(       \
                    afb[i], bfc[j], acc[4 + i][j], 0, 0, 0);                   \
        __builtin_amdgcn_s_setprio(0);                                         \
        __builtin_amdgcn_s_barrier();                                          \
        __builtin_amdgcn_sched_barrier(0);                                     \
    }

    // ---- prologue ----
    // A(0), A(1) converted+written; A(2) loads left in flight.
    LOAD_A(0)
    asm volatile("s_waitcnt vmcnt(0)" ::: "memory");
    WRITE_A(0)
    LOAD_A(1)
    asm volatile("s_waitcnt vmcnt(0)" ::: "memory");
    WRITE_A(1)
    LOAD_A(2)
    STAGE_B(0) STAGE_B(1) STAGE_B(2)
    // queue: [A4(2), B0ab, B1ab, B2ab] = 10; vmcnt(4) completes A4(2)+B0ab,
    // leaves B1ab,B2ab — matches steady-state "newest B pairs outstanding".
    asm volatile("s_waitcnt vmcnt(4)" ::: "memory");
    asm volatile("s_waitcnt lgkmcnt(0)" ::: "memory");
    __builtin_amdgcn_s_barrier();
    __builtin_amdgcn_sched_barrier(0);

    bf16x8 af0[4], bf0[4], af1[4], bf1[4];
#pragma unroll
    for (int j = 0; j < 4; ++j)
        bf0[j] = *(const bf16x8*)(lds + boff + j * 512);
#pragma unroll
    for (int i = 0; i < 4; ++i)
        af0[i] = *(const bf16x8*)(lds + aoff + i * 512);

    for (int t = 0; t < NT; t += 2) {
        BODY(t,     af0, bf0, af1, bf1)
        BODY(t + 1, af1, bf1, af0, bf0)
    }
#undef BODY
#undef STAGE_B
#undef WRITE_A
#undef LOAD_A

    // epilogue: C = acc + bias
    const int crow0 = bm * TBM + wm * 128;
    const int ccol0 = bn * TBN + wn * 64;
    const int rl = lane >> 4;
    const int cl = lane & 15;
#pragma unroll
    for (int j = 0; j < 4; ++j) {
        const int col = ccol0 + j * 16 + cl;
        const float bv = bias[col];
#pragma unroll
        for (int i = 0; i < 8; ++i) {
            const int row = crow0 + i * 16 + rl * 4;
            float* cp = C + (size_t)row * N_DIM + col;
#pragma unroll
            for (int r = 0; r < 4; ++r)
                cp[(size_t)r * N_DIM] = acc[i][j][r] + bv;
        }
    }
}

// ---------------------------------------------------------------------------
extern "C" void kernel_launch(void* const* d_in, const int* in_sizes, int n_in,
                              void* d_out, int out_size, void* d_ws, size_t ws_size,
                              hipStream_t stream) {
    const float* x      = (const float*)d_in[0];
    const int*   pw     = (const int*)d_in[1];
    const float* scales = (const float*)d_in[2];
    const float* zps    = (const float*)d_in[3];
    const float* bias   = (const float*)d_in[4];
    float* out = (float*)d_out;

    ushort* wb = (ushort*)d_ws;                        // 33.5 MB bf16 weights

    {
        int np4 = (N_DIM * K_DIM / 2) / 4;
        dequant_w_kernel<<<np4 / 256, 256, 0, stream>>>(
            (const int4*)pw, scales, zps, (uint4*)wb, np4);
    }

    // fused GEMM reads x fp32 directly (no convert pass, no xb buffer)
    int nblk = (M_DIM / TBM) * (N_DIM / TBN);          // 32*16 = 512
    gemm_fused_256<<<nblk, 512, 0, stream>>>(x, wb, bias, out);
}

// Round 8
// 461.550 us; speedup vs baseline: 1.3345x; 1.3345x over previous
//
#include <hip/hip_runtime.h>
#include <cstdint>
#include <cstddef>

#define M_DIM 8192
#define N_DIM 4096
#define K_DIM 4096
#define CHUNK_M 4096   // chunked fallback if ws can't hold full converted x

typedef __attribute__((ext_vector_type(8))) short bf16x8;
typedef __attribute__((ext_vector_type(4))) float floatx4;

__device__ __forceinline__ ushort f2bf_rne(float f) {
    union { float f; uint32_t u; } a;
    a.f = f;
    uint32_t u = a.u;
    uint32_t r = (u + 0x7fffu + ((u >> 16) & 1u)) >> 16;
    return (ushort)r;
}

__device__ __forceinline__ uint32_t pk_bf_trunc(float f0, float f1) {
    return __builtin_amdgcn_perm(__float_as_uint(f1), __float_as_uint(f0),
                                 0x07060302u);
}

// ---------------------------------------------------------------------------
// Kernel 1: packed int4 (one signed byte per int32) -> dequant -> bf16 (RNE)
// ---------------------------------------------------------------------------
__global__ void dequant_w_kernel(const int4* __restrict__ pw,
                                 const float* __restrict__ scales,
                                 const float* __restrict__ zps,
                                 uint4* __restrict__ wb, int np4) {
    int p4 = blockIdx.x * blockDim.x + threadIdx.x;
    if (p4 >= np4) return;
    int p = p4 * 4;
    int g = p >> 18;
    float s = scales[g];
    float b = -zps[g] * s;
    int4 v = pw[p4];
    int vv[4] = { v.x, v.y, v.z, v.w };
    ushort o[8];
#pragma unroll
    for (int j = 0; j < 4; ++j) {
        int lo = ((int)((uint32_t)vv[j] << 28)) >> 28;
        int hi = ((int)((uint32_t)vv[j] << 24)) >> 28;
        o[2 * j]     = f2bf_rne(fmaf((float)lo, s, b));
        o[2 * j + 1] = f2bf_rne(fmaf((float)hi, s, b));
    }
    uint4 st;
    st.x = (uint32_t)o[0] | ((uint32_t)o[1] << 16);
    st.y = (uint32_t)o[2] | ((uint32_t)o[3] << 16);
    st.z = (uint32_t)o[4] | ((uint32_t)o[5] << 16);
    st.w = (uint32_t)o[6] | ((uint32_t)o[7] << 16);
    wb[p4] = st;
}

// ---------------------------------------------------------------------------
// Kernel 2: x fp32 -> bf16 (RNE)
// ---------------------------------------------------------------------------
__global__ void convert_x_kernel(const float4* __restrict__ x4,
                                 ushort4* __restrict__ out4, int n4) {
    int i = blockIdx.x * blockDim.x + threadIdx.x;
    if (i >= n4) return;
    float4 v = x4[i];
    ushort4 o;
    o.x = f2bf_rne(v.x);
    o.y = f2bf_rne(v.y);
    o.z = f2bf_rne(v.z);
    o.w = f2bf_rne(v.w);
    out4[i] = o;
}

// ---------------------------------------------------------------------------
// Kernel 3a: 256x256 pipelined bf16 GEMM (R5 schedule + FULL next-tile
// register prefetch -> zero in-step LDS waits).
// A [M][K] bf16 row-major, B [N][K] bf16 row-major. C = A*B^T + bias.
// 512 threads = 8 waves (2M x 4N), per-wave 128x64 output, acc[8][4].
//
// R8 schedule: step t computes ALL 32 MFMA of tile t from regs loaded in
// step t-1, and issues the 12 ds_reads for tile t+1's frags (3 groups of 4,
// interleaved between MFMA clusters). NO lgkmcnt in-step: reads have a full
// step (~2000 cyc) to drain under the MFMAs; compiler's auto-wait at
// next-step first-use finds them retired. (R5's mid-step lgkmcnt(8) was the
// joint-stall: both SIMD waves blocked on same-step reads -> 43% matrix
// idle.) Only syncs per step: vmcnt(4) + s_barrier.
//
// Invariants (ring of 4 slots):
//   stage(t+3) issued in step t into slot (t+3)&3 = slot of t-1, whose
//   readers (frag reads for t-1, issued step t-2) completed before their
//   use in step t-1 < beta(t-1).  Reads in step t target slot (t+1)&3;
//   writes in flight target (t+2)&3, (t+3)&3 - distinct mod 4.
//   vmcnt(4) at end of step t certifies stage(t+2) landed (4 loads of
//   t+3 may fly); BODY(t+1)'s reads of tile t+2 are therefore safe.
//
// T2 swizzle (BK=32, rows = 4 x 16B slots): slot' = slot ^ ((row>>1)&3),
// applied as inverse-swizzled GLOBAL source (LDS dest stays linear for
// global_load_lds) + swizzled fragment-read address (per-lane constant).
// ---------------------------------------------------------------------------
#define TBM 256
#define TBN 256
#define TBK 32
#define NT  (K_DIM / TBK)        // 128 K-steps
#define A_E 8192                 // elements of A per slot (256*32)
#define SLOT_E 16384             // elements per ring slot (A + B)

__global__ __launch_bounds__(512, 2)
void gemm_bf16_256(const ushort* __restrict__ A,
                   const ushort* __restrict__ B,
                   const float* __restrict__ bias,
                   float* __restrict__ C) {
    __shared__ ushort lds[4 * SLOT_E];   // 128 KiB -> 1 block/CU, 8 waves

    const int tid  = threadIdx.x;
    const int lane = tid & 63;
    const int wave = tid >> 6;
    const int wm   = wave >> 2;          // 0..1
    const int wn   = wave & 3;           // 0..3

    // T1: XCD-chunked bijective swizzle (nwg % 8 == 0)
    const int nwg = gridDim.x;
    const int cpx = nwg >> 3;
    const int bid = blockIdx.x;
    const int swz = (bid & 7) * cpx + (bid >> 3);
    const int bn  = swz & (N_DIM / TBN - 1);
    const int bm  = swz / (N_DIM / TBN);

    const ushort* Ab = A + (size_t)(bm * TBM) * K_DIM;
    const ushort* Bb = B + (size_t)(bn * TBN) * K_DIM;

    // staging: thread tid covers LDS offset tid*16B of an 8KB part
    // -> part row tid>>2 (0..127); T2: fetch INVERSE-swizzled global k-chunk
    const int srow = tid >> 2;
    const int scol = (((tid & 3) ^ ((tid >> 3) & 3)) * 8);
    const ushort* gA0 = Ab + (size_t)srow * K_DIM + scol;
    const ushort* gA1 = gA0 + (size_t)128 * K_DIM;
    const ushort* gB0 = Bb + (size_t)srow * K_DIM + scol;
    const ushort* gB1 = gB0 + (size_t)128 * K_DIM;
    const int wdst = wave * 512;         // this wave's 1KB within a part

    // MFMA fragment addressing: T2 swizzled slot, constant per lane
    const int frow = lane & 15;
    const int fcol = (((lane >> 4) ^ ((frow >> 1) & 3)) * 8);
    const int aoff = (wm * 128 + frow) * TBK + fcol;          // within A region
    const int boff = A_E + (wn * 64 + frow) * TBK + fcol;     // within B region

    floatx4 acc[8][4] = {};

#define STAGE_A(tt)                                                           \
    {                                                                          \
        const int k0s = ((tt) & (NT - 1)) * TBK;                               \
        ushort* d = lds + ((tt) & 3) * SLOT_E + wdst;                          \
        __builtin_amdgcn_global_load_lds(                                      \
            (const __attribute__((address_space(1))) void*)(gA0 + k0s),        \
            (__attribute__((address_space(3))) void*)d, 16, 0, 0);             \
        __builtin_amdgcn_global_load_lds(                                      \
            (const __attribute__((address_space(1))) void*)(gA1 + k0s),        \
            (__attribute__((address_space(3))) void*)(d + 4096), 16, 0, 0);    \
    }
#define STAGE_B(tt)                                                           \
    {                                                                          \
        const int k0s = ((tt) & (NT - 1)) * TBK;                               \
        ushort* d = lds + ((tt) & 3) * SLOT_E + A_E + wdst;                    \
        __builtin_amdgcn_global_load_lds(                                      \
            (const __attribute__((address_space(1))) void*)(gB0 + k0s),        \
            (__attribute__((address_space(3))) void*)d, 16, 0, 0);             \
        __builtin_amdgcn_global_load_lds(                                      \
            (const __attribute__((address_space(1))) void*)(gB1 + k0s),        \
            (__attribute__((address_space(3))) void*)(d + 4096), 16, 0, 0);    \
    }

// one K-step: consume tile T's frags (afc[8], bfc[4], loaded last step);
// prefetch tile T+1's frags into afn[8]/bfn[4]; stage tile T+3.
#define BODY(T, afc, bfc, afn, bfn)                                           \
    {                                                                          \
        const ushort* bnxt = lds + (((T) + 1) & 3) * SLOT_E;                   \
        /* G1: afn[0..3] + stage A(t+3) */                                     \
        _Pragma("unroll")                                                      \
        for (int i = 0; i < 4; ++i)                                            \
            afn[i] = *(const bf16x8*)(bnxt + aoff + i * 512);                  \
        STAGE_A((T) + 3)                                                       \
        __builtin_amdgcn_sched_barrier(0);                                     \
        __builtin_amdgcn_s_setprio(1);                                         \
        _Pragma("unroll")                                                      \
        for (int i = 0; i < 2; ++i)                                            \
            _Pragma("unroll")                                                  \
            for (int j = 0; j < 4; ++j)                                        \
                acc[i][j] = __builtin_amdgcn_mfma_f32_16x16x32_bf16(           \
                    afc[i], bfc[j], acc[i][j], 0, 0, 0);                       \
        __builtin_amdgcn_s_setprio(0);                                         \
        __builtin_amdgcn_sched_barrier(0);                                     \
        /* G2: bfn[0..3] + stage B(t+3) */                                     \
        _Pragma("unroll")                                                      \
        for (int j = 0; j < 4; ++j)                                            \
            bfn[j] = *(const bf16x8*)(bnxt + boff + j * 512);                  \
        STAGE_B((T) + 3)                                                       \
        __builtin_amdgcn_sched_barrier(0);                                     \
        __builtin_amdgcn_s_setprio(1);                                         \
        _Pragma("unroll")                                                      \
        for (int i = 2; i < 4; ++i)                                            \
            _Pragma("unroll")                                                  \
            for (int j = 0; j < 4; ++j)                                        \
                acc[i][j] = __builtin_amdgcn_mfma_f32_16x16x32_bf16(           \
                    afc[i], bfc[j], acc[i][j], 0, 0, 0);                       \
        __builtin_amdgcn_s_setprio(0);                                         \
        __builtin_amdgcn_sched_barrier(0);                                     \
        /* G3: afn[4..7] */                                                    \
        _Pragma("unroll")                                                      \
        for (int i = 4; i < 8; ++i)                                            \
            afn[i] = *(const bf16x8*)(bnxt + aoff + i * 512);                  \
        __builtin_amdgcn_sched_barrier(0);                                     \
        __builtin_amdgcn_s_setprio(1);                                         \
        _Pragma("unroll")                                                      \
        for (int i = 4; i < 8; ++i)                                            \
            _Pragma("unroll")                                                  \
            for (int j = 0; j < 4; ++j)                                        \
                acc[i][j] = __builtin_amdgcn_mfma_f32_16x16x32_bf16(           \
                    afc[i], bfc[j], acc[i][j], 0, 0, 0);                       \
        __builtin_amdgcn_s_setprio(0);                                         \
        /* certify stage(t+2) landed (t+3's 4 loads may fly) */                \
        asm volatile("s_waitcnt vmcnt(4)" ::: "memory");                       \
        __builtin_amdgcn_s_barrier();                                          \
        __builtin_amdgcn_sched_barrier(0);                                     \
    }

    // prologue: tiles 0,1,2 in flight; vmcnt(4) -> tiles 0,1 landed (2 flying)
    STAGE_A(0) STAGE_B(0)
    STAGE_A(1) STAGE_B(1)
    STAGE_A(2) STAGE_B(2)
    asm volatile("s_waitcnt vmcnt(4)" ::: "memory");
    __builtin_amdgcn_s_barrier();
    __builtin_amdgcn_sched_barrier(0);

    // initial fragment set: tile 0 (slot 0). Tile 1 is also certified landed,
    // so BODY(0)'s prefetch of tile 1 is safe.
    bf16x8 af0[8], bf0[4], af1[8], bf1[4];
#pragma unroll
    for (int j = 0; j < 4; ++j)
        bf0[j] = *(const bf16x8*)(lds + boff + j * 512);
#pragma unroll
    for (int i = 0; i < 8; ++i)
        af0[i] = *(const bf16x8*)(lds + aoff + i * 512);

    for (int t = 0; t < NT; t += 2) {
        BODY(t,     af0, bf0, af1, bf1)
        BODY(t + 1, af1, bf1, af0, bf0)
    }
#undef BODY
#undef STAGE_A
#undef STAGE_B

    // epilogue: C = acc + bias
    const int crow0 = bm * TBM + wm * 128;
    const int ccol0 = bn * TBN + wn * 64;
    const int rl = lane >> 4;
    const int cl = lane & 15;
#pragma unroll
    for (int j = 0; j < 4; ++j) {
        const int col = ccol0 + j * 16 + cl;
        const float bv = bias[col];
#pragma unroll
        for (int i = 0; i < 8; ++i) {
            const int row = crow0 + i * 16 + rl * 4;
            float* cp = C + (size_t)row * N_DIM + col;
#pragma unroll
            for (int r = 0; r < 4; ++r)
                cp[(size_t)r * N_DIM] = acc[i][j][r] + bv;
        }
    }
}

// ---------------------------------------------------------------------------
// Kernel 3b (fallback if ws too small): fused fp32-A GEMM, 128x128 tile.
// ---------------------------------------------------------------------------
#define BM 128
#define BN 128
#define BK 32

__global__ void gemm_fused_kernel(const float* __restrict__ X,
                                  const ushort* __restrict__ B,
                                  const float* __restrict__ bias,
                                  float* __restrict__ C) {
    __shared__ ushort As[BM * BK];
    __shared__ ushort Bs[BN * BK];

    const int tid  = threadIdx.x;
    const int lane = tid & 63;
    const int wave = tid >> 6;
    const int wm   = wave >> 1;
    const int wn   = wave & 1;
    const int bm   = blockIdx.y;
    const int bn   = blockIdx.x;

    const int ar = tid >> 2;
    const int ac = (tid & 3) * 8;
    const float* xp0 = X + (size_t)(bm * BM + ar) * K_DIM + ac;
    const float* xp1 = xp0 + (size_t)64 * K_DIM;
    ushort* as0 = As + ar * BK + ac;
    ushort* as1 = as0 + 64 * BK;

    const int scol = (lane & 3) * 8;
    const ushort* Bb = B + (size_t)(bn * BN) * K_DIM;

    floatx4 acc[4][4] = {};

    for (int k0 = 0; k0 < K_DIM; k0 += BK) {
        float4 a0 = *(const float4*)(xp0 + k0);
        float4 a1 = *(const float4*)(xp0 + k0 + 4);
        float4 b0 = *(const float4*)(xp1 + k0);
        float4 b1 = *(const float4*)(xp1 + k0 + 4);
#pragma unroll
        for (int q = 0; q < 2; ++q) {
            const int chunk = wave * 2 + q;
            const int r = chunk * 16 + (lane >> 2);
            const ushort* gb = Bb + (size_t)r * K_DIM + k0 + scol;
            __builtin_amdgcn_global_load_lds(
                (const __attribute__((address_space(1))) void*)gb,
                (__attribute__((address_space(3))) void*)(Bs + chunk * 512),
                16, 0, 0);
        }
        uint4 w0, w1;
        w0.x = pk_bf_trunc(a0.x, a0.y);
        w0.y = pk_bf_trunc(a0.z, a0.w);
        w0.z = pk_bf_trunc(a1.x, a1.y);
        w0.w = pk_bf_trunc(a1.z, a1.w);
        w1.x = pk_bf_trunc(b0.x, b0.y);
        w1.y = pk_bf_trunc(b0.z, b0.w);
        w1.z = pk_bf_trunc(b1.x, b1.y);
        w1.w = pk_bf_trunc(b1.z, b1.w);
        *(uint4*)as0 = w0;
        *(uint4*)as1 = w1;

        __syncthreads();

        bf16x8 af[4], bfr[4];
        const int frow = lane & 15;
        const int fcol = (lane >> 4) * 8;
#pragma unroll
        for (int i = 0; i < 4; ++i) {
            af[i]  = *(const bf16x8*)(As + (wm * 64 + i * 16 + frow) * BK + fcol);
            bfr[i] = *(const bf16x8*)(Bs + (wn * 64 + i * 16 + frow) * BK + fcol);
        }
#pragma unroll
        for (int i = 0; i < 4; ++i)
#pragma unroll
            for (int j = 0; j < 4; ++j)
                acc[i][j] = __builtin_amdgcn_mfma_f32_16x16x32_bf16(
                    af[i], bfr[j], acc[i][j], 0, 0, 0);
        __syncthreads();
    }

    const int crow0 = bm * BM + wm * 64;
    const int ccol0 = bn * BN + wn * 64;
    const int rl = lane >> 4;
    const int cl = lane & 15;
#pragma unroll
    for (int j = 0; j < 4; ++j) {
        const int col = ccol0 + j * 16 + cl;
        const float bv = bias[col];
#pragma unroll
        for (int i = 0; i < 4; ++i) {
            const int row = crow0 + i * 16 + rl * 4;
            float* cp = C + (size_t)row * N_DIM + col;
#pragma unroll
            for (int r = 0; r < 4; ++r)
                cp[(size_t)r * N_DIM] = acc[i][j][r] + bv;
        }
    }
}

// ---------------------------------------------------------------------------
extern "C" void kernel_launch(void* const* d_in, const int* in_sizes, int n_in,
                              void* d_out, int out_size, void* d_ws, size_t ws_size,
                              hipStream_t stream) {
    const float* x      = (const float*)d_in[0];
    const int*   pw     = (const int*)d_in[1];
    const float* scales = (const float*)d_in[2];
    const float* zps    = (const float*)d_in[3];
    const float* bias   = (const float*)d_in[4];
    float* out = (float*)d_out;

    ushort* wb = (ushort*)d_ws;                        // 33.5 MB

    {
        int np4 = (N_DIM * K_DIM / 2) / 4;
        dequant_w_kernel<<<np4 / 256, 256, 0, stream>>>(
            (const int4*)pw, scales, zps, (uint4*)wb, np4);
    }

    const size_t need_full  = ((size_t)N_DIM * K_DIM + (size_t)M_DIM * K_DIM) * 2;
    const size_t need_chunk = ((size_t)N_DIM * K_DIM + (size_t)CHUNK_M * K_DIM) * 2;

    if (ws_size >= need_full) {
        // full path: convert all of x once, single GEMM over M=8192
        ushort* xb = wb + (size_t)N_DIM * K_DIM;       // 67.1 MB
        int n4 = (M_DIM * K_DIM) / 4;
        convert_x_kernel<<<n4 / 256, 256, 0, stream>>>(
            (const float4*)x, (ushort4*)xb, n4);
        int nblk = (M_DIM / TBM) * (N_DIM / TBN);      // 32*16 = 512
        gemm_bf16_256<<<nblk, 512, 0, stream>>>(xb, wb, bias, out);
    } else if (ws_size >= need_chunk) {
        // chunked path
        ushort* xb = wb + (size_t)N_DIM * K_DIM;
        for (int c = 0; c < M_DIM / CHUNK_M; ++c) {
            const float* xc = x + (size_t)c * CHUNK_M * K_DIM;
            float* oc = out + (size_t)c * CHUNK_M * N_DIM;
            int n4 = (CHUNK_M * K_DIM) / 4;
            convert_x_kernel<<<n4 / 256, 256, 0, stream>>>(
                (const float4*)xc, (ushort4*)xb, n4);
            int nblk = (CHUNK_M / TBM) * (N_DIM / TBN);
            gemm_bf16_256<<<nblk, 512, 0, stream>>>(xb, wb, bias, oc);
        }
    } else {
        // fallback: fused conversion
        dim3 grid(N_DIM / BN, M_DIM / BM);
        gemm_fused_kernel<<<grid, 256, 0, stream>>>(x, wb, bias, out);
    }
}